// Round 10
// baseline (578.762 us; speedup 1.0000x reference)
//
#include <hip/hip_runtime.h>

#define NN 50000
#define EE 800000
#define HH 4

typedef __attribute__((ext_vector_type(8))) short short8v;     // 8 bf16 = 4 VGPR
typedef __attribute__((ext_vector_type(4))) float f32x4;
typedef __attribute__((ext_vector_type(4))) unsigned short ushort4v;

__device__ __forceinline__ float b2f(unsigned short u) {
    return __uint_as_float(((unsigned int)u) << 16);
}
__device__ __forceinline__ unsigned short f2b(float f) {
    unsigned int x = __float_as_uint(f);
    x += 0x7fffu + ((x >> 16) & 1u);
    return (unsigned short)(x >> 16);
}

// ------- projection GEMM, K=128 fully LDS-resident: C = A @ Bt^T + el/er -----
// BM=128 rows/block, N = NG*128 cols processed in NG groups of 128.
// A staged once; A-frags hoisted to regs; As region reused as C-stage.
// B for group g+1 prefetched into regs during group g's MFMA.
// HPG heads per group (1: D=128, 2: D=64). el/er written per group.
template<int NG, int HPG>
__global__ __launch_bounds__(256) void pgemm_k(
    const unsigned short* __restrict__ A, const unsigned short* __restrict__ Bt,
    unsigned short* __restrict__ C,
    const float* __restrict__ al, const float* __restrict__ ar,
    float* __restrict__ el, float* __restrict__ er, int M)
{
    constexpr int K = 128, N = NG * 128, LDA = 136;
    __shared__ unsigned short smem[2 * 128 * LDA];   // 69.6 KB
    unsigned short* As = smem;                 // A stage, then C stage
    unsigned short* Bs = smem + 128 * LDA;
    const int t  = threadIdx.x;
    const int m0 = blockIdx.x * 128;
    const int w  = t >> 6, l = t & 63;
    const int lr = l & 15, lk8 = (l >> 4) * 8;
    const int wbase = w * 32;

    // ---- stage A: 128x128 bf16, 8x16B chunks per thread ----
    #pragma unroll
    for (int cc = 0; cc < 8; ++cc) {
        int c = t + cc * 256;
        int row = c >> 4, seg = (c & 15) * 8;
        int gm = m0 + row;
        short8v v = (short8v)0;
        if (gm < M)
            v = *reinterpret_cast<const short8v*>(&A[(size_t)gm * K + seg]);
        *reinterpret_cast<short8v*>(&As[row * LDA + seg]) = v;
    }
    __syncthreads();
    // ---- hoist A-frags: 4 k-steps x 2 row-halves -> 32 VGPR ----
    short8v afr[4][2];
    #pragma unroll
    for (int kk4 = 0; kk4 < 4; ++kk4)
        #pragma unroll
        for (int rr = 0; rr < 2; ++rr)
            afr[kk4][rr] = *reinterpret_cast<const short8v*>(
                &As[(wbase + rr * 16 + lr) * LDA + kk4 * 32 + lk8]);

    // ---- prefetch B group 0 into regs ----
    short8v rb[8];
    auto LOADB = [&](int g) {
        #pragma unroll
        for (int cc = 0; cc < 8; ++cc) {
            int c = t + cc * 256;
            int row = c >> 4, seg = (c & 15) * 8;
            rb[cc] = *reinterpret_cast<const short8v*>(
                &Bt[(size_t)(g * 128 + row) * K + seg]);
        }
    };
    LOADB(0);

    for (int g = 0; g < NG; ++g) {
        __syncthreads();   // prev group's b-reads + C readback done; a-frags read
        #pragma unroll
        for (int cc = 0; cc < 8; ++cc) {
            int c = t + cc * 256;
            *reinterpret_cast<short8v*>(&Bs[(c >> 4) * LDA + (c & 15) * 8]) = rb[cc];
        }
        __syncthreads();
        if (g + 1 < NG) LOADB(g + 1);          // hide under MFMA

        f32x4 acc[2][8];
        #pragma unroll
        for (int rr = 0; rr < 2; ++rr)
            #pragma unroll
            for (int nb = 0; nb < 8; ++nb) acc[rr][nb] = (f32x4)0.f;
        #pragma unroll
        for (int kk4 = 0; kk4 < 4; ++kk4) {
            #pragma unroll
            for (int nb = 0; nb < 8; ++nb) {
                short8v b = *reinterpret_cast<const short8v*>(
                    &Bs[(nb * 16 + lr) * LDA + kk4 * 32 + lk8]);
                acc[0][nb] = __builtin_amdgcn_mfma_f32_16x16x32_bf16(
                    afr[kk4][0], b, acc[0][nb], 0, 0, 0);
                acc[1][nb] = __builtin_amdgcn_mfma_f32_16x16x32_bf16(
                    afr[kk4][1], b, acc[1][nb], 0, 0, 0);
            }
        }

        // ---- fused el/er for this group's head(s) ----
        constexpr int nbh = 8 / HPG;
        constexpr int Dd  = (HPG == 1) ? 128 : 64;
        #pragma unroll
        for (int hh = 0; hh < HPG; ++hh) {
            int head = g * HPG + hh;
            #pragma unroll
            for (int rr = 0; rr < 2; ++rr) {
                float pl[4] = {}, pr[4] = {};
                #pragma unroll
                for (int nb = 0; nb < nbh; ++nb) {
                    float alv = al[head * Dd + nb * 16 + lr];
                    float arv = ar[head * Dd + nb * 16 + lr];
                    #pragma unroll
                    for (int r = 0; r < 4; ++r) {
                        float z = acc[rr][hh * nbh + nb][r];
                        pl[r] = fmaf(z, alv, pl[r]);
                        pr[r] = fmaf(z, arv, pr[r]);
                    }
                }
                #pragma unroll
                for (int r = 0; r < 4; ++r) {
                    #pragma unroll
                    for (int o = 1; o < 16; o <<= 1) {
                        pl[r] += __shfl_xor(pl[r], o);
                        pr[r] += __shfl_xor(pr[r], o);
                    }
                }
                if (lr == 0) {
                    #pragma unroll
                    for (int r = 0; r < 4; ++r) {
                        int gm = m0 + wbase + rr * 16 + (l >> 4) * 4 + r;
                        if (gm < M) {
                            el[gm * HH + head] = pl[r];
                            er[gm * HH + head] = pr[r];
                        }
                    }
                }
            }
        }

        // ---- stage C tile into As region, then 16B coalesced stores ----
        #pragma unroll
        for (int rr = 0; rr < 2; ++rr)
            #pragma unroll
            for (int nb = 0; nb < 8; ++nb)
                #pragma unroll
                for (int r = 0; r < 4; ++r) {
                    int row = wbase + rr * 16 + (l >> 4) * 4 + r;
                    As[row * LDA + nb * 16 + lr] = f2b(acc[rr][nb][r]);
                }
        __syncthreads();
        #pragma unroll
        for (int cc = 0; cc < 8; ++cc) {
            int c = t + cc * 256;
            int row = c >> 4, seg = (c & 15) * 8;
            int gm = m0 + row;
            if (gm < M)
                *reinterpret_cast<short8v*>(&C[(size_t)gm * N + g * 128 + seg]) =
                    *reinterpret_cast<const short8v*>(&As[row * LDA + seg]);
        }
    }
}

// ---------------- dense bf16 MFMA GEMM (K=512, N=128) ------------------------
// BM=128, BN=128, BK=64; register double-buffer; LDS-staged C-write.
template<bool ACT>
__global__ __launch_bounds__(256) void mgemm_k(
    const unsigned short* __restrict__ A, const unsigned short* __restrict__ Bt,
    const float* __restrict__ bias, unsigned short* __restrict__ C,
    int M, int N, int K, float slope)
{
    constexpr int BM = 128;
    __shared__ unsigned short smem[BM * 72 + 128 * 72];
    unsigned short* As = smem;
    unsigned short* Bs = smem + BM * 72;
    unsigned short* Cs = smem;                // after last barrier
    const int t   = threadIdx.x;
    const int m0  = blockIdx.y * BM;
    const int n0  = blockIdx.x * 128;
    const int w   = t >> 6;
    const int l   = t & 63;
    const int lr  = l & 15;
    const int lk8 = (l >> 4) * 8;
    const int wbase = w * 32;

    f32x4 acc[2][8];
    #pragma unroll
    for (int rr = 0; rr < 2; ++rr)
        #pragma unroll
        for (int i = 0; i < 8; ++i) acc[rr][i] = (f32x4)0.f;

    short8v ra[4], rb[4];
    auto LOAD = [&](int k0) {
        #pragma unroll
        for (int cc = 0; cc < 4; ++cc) {
            int c = t + cc * 256;
            int row = c >> 3, seg = (c & 7) * 8;
            int gm = m0 + row;
            ra[cc] = (short8v)0;
            if (gm < M)
                ra[cc] = *reinterpret_cast<const short8v*>(
                    &A[(size_t)gm * K + k0 + seg]);
        }
        #pragma unroll
        for (int cc = 0; cc < 4; ++cc) {
            int c = t + cc * 256;
            int row = c >> 3, seg = (c & 7) * 8;
            rb[cc] = *reinterpret_cast<const short8v*>(
                &Bt[(size_t)(n0 + row) * K + k0 + seg]);
        }
    };

    LOAD(0);
    for (int k0 = 0; k0 < K; k0 += 64) {
        #pragma unroll
        for (int cc = 0; cc < 4; ++cc) {
            int c = t + cc * 256;
            *reinterpret_cast<short8v*>(&As[(c >> 3) * 72 + (c & 7) * 8]) = ra[cc];
        }
        #pragma unroll
        for (int cc = 0; cc < 4; ++cc) {
            int c = t + cc * 256;
            *reinterpret_cast<short8v*>(&Bs[(c >> 3) * 72 + (c & 7) * 8]) = rb[cc];
        }
        __syncthreads();
        if (k0 + 64 < K) LOAD(k0 + 64);
        #pragma unroll
        for (int kk = 0; kk < 64; kk += 32) {
            short8v a[2];
            #pragma unroll
            for (int rr = 0; rr < 2; ++rr)
                a[rr] = *reinterpret_cast<const short8v*>(
                    &As[(wbase + rr * 16 + lr) * 72 + kk + lk8]);
            #pragma unroll
            for (int nb = 0; nb < 8; ++nb) {
                short8v b = *reinterpret_cast<const short8v*>(
                    &Bs[(nb * 16 + lr) * 72 + kk + lk8]);
                #pragma unroll
                for (int rr = 0; rr < 2; ++rr)
                    acc[rr][nb] = __builtin_amdgcn_mfma_f32_16x16x32_bf16(
                        a[rr], b, acc[rr][nb], 0, 0, 0);
            }
        }
        __syncthreads();
    }

    #pragma unroll
    for (int rr = 0; rr < 2; ++rr)
        #pragma unroll
        for (int nb = 0; nb < 8; ++nb)
            #pragma unroll
            for (int r = 0; r < 4; ++r) {
                int row = wbase + rr * 16 + (l >> 4) * 4 + r;
                int gn = n0 + nb * 16 + lr;
                float v = acc[rr][nb][r];
                if (ACT) { v += bias[gn]; v = v >= 0.f ? v : slope * v; }
                Cs[row * 136 + nb * 16 + lr] = f2b(v);
            }
    __syncthreads();
    #pragma unroll
    for (int cc = 0; cc < 8; ++cc) {
        int c = t + cc * 256;
        int row = c >> 4, seg = (c & 15) * 8;
        int gm = m0 + row;
        if (gm < M) {
            short8v v = *reinterpret_cast<const short8v*>(&Cs[row * 136 + seg]);
            *reinterpret_cast<short8v*>(&C[(size_t)gm * N + n0 + seg]) = v;
        }
    }
}

// ---------------- fused weight/feature prep (1 launch) -----------------------
#define PREP_T 1796608
__global__ __launch_bounds__(256) void prep_k(
    const float* __restrict__ n_feat, const float* __restrict__ d0_W,
    const float* __restrict__ d1_W, const float* __restrict__ g0_W,
    const float* __restrict__ g1_W, const float* __restrict__ g2_W,
    unsigned short* __restrict__ xF, unsigned short* __restrict__ d0t,
    unsigned short* __restrict__ d1t, unsigned short* __restrict__ g0t,
    unsigned short* __restrict__ g1t, unsigned short* __restrict__ g2t)
{
    int i = blockIdx.x * blockDim.x + threadIdx.x;
    if (i >= PREP_T) return;
    if (i < 1632768) {
        const float* src; unsigned short* dstp; int j;
        if (i < 1600000)      { src = n_feat; dstp = xF;  j = i; }
        else if (i < 1616384) { src = d0_W;   dstp = d0t; j = i - 1600000; }
        else                  { src = d1_W;   dstp = d1t; j = i - 1616384; }
        float4 v = reinterpret_cast<const float4*>(src)[j];
        ushort4v u;
        u[0] = f2b(v.x); u[1] = f2b(v.y); u[2] = f2b(v.z); u[3] = f2b(v.w);
        reinterpret_cast<ushort4v*>(dstp)[j] = u;
    } else {
        const float* W; unsigned short* Wt; int j, K = 128;
        if (i < 1698304)      { W = g0_W; Wt = g0t; j = i - 1632768; }
        else if (i < 1763840) { W = g1_W; Wt = g1t; j = i - 1698304; }
        else                  { W = g2_W; Wt = g2t; j = i - 1763840; }
        int N = (i < 1763840) ? 512 : 256;
        int n = j / K, k = j - n * K;
        Wt[j] = f2b(W[(size_t)k * N + n]);
    }
}

// --------------- CSR build ---------------------------------------------------
__global__ void hist_k(const int* __restrict__ dst, int* __restrict__ cnt)
{
    int i = blockIdx.x * blockDim.x + threadIdx.x;
    if (i < EE / 2) {
        int2 d = reinterpret_cast<const int2*>(dst)[i];
        atomicAdd(&cnt[d.x], 1);
        atomicAdd(&cnt[d.y], 1);
    }
}

#define SCAN_B 196   // ceil(50000/256)
__global__ __launch_bounds__(256) void scan1_k(const int* __restrict__ cnt,
                                               int* __restrict__ offs,
                                               int* __restrict__ bsum)
{
    __shared__ int sh[256];
    int b = blockIdx.x, t = threadIdx.x, i = b * 256 + t;
    int v = (i < NN) ? cnt[i] : 0;
    sh[t] = v;
    __syncthreads();
    #pragma unroll
    for (int o = 1; o < 256; o <<= 1) {
        int add = (t >= o) ? sh[t - o] : 0;
        __syncthreads();
        sh[t] += add;
        __syncthreads();
    }
    if (i < NN) offs[i] = sh[t] - v;
    if (t == 255) bsum[b] = sh[t];
}

__global__ __launch_bounds__(256) void scan2_k(int* __restrict__ bsum)
{
    __shared__ int sh[256];
    int t = threadIdx.x;
    int v = (t < SCAN_B) ? bsum[t] : 0;
    sh[t] = v;
    __syncthreads();
    #pragma unroll
    for (int o = 1; o < 256; o <<= 1) {
        int add = (t >= o) ? sh[t - o] : 0;
        __syncthreads();
        sh[t] += add;
        __syncthreads();
    }
    if (t < SCAN_B) bsum[t] = sh[t] - v;
}

__global__ __launch_bounds__(256) void scan3_k(int* __restrict__ offs,
                                               const int* __restrict__ bsum,
                                               int* __restrict__ curs)
{
    int b = blockIdx.x, t = threadIdx.x, i = b * 256 + t;
    if (i < NN) { offs[i] += bsum[b]; curs[i] = 0; }
    if (i == NN - 1) offs[NN] = EE;
}

__global__ void scatter_k(const int* __restrict__ src, const int* __restrict__ dst,
                          const int* __restrict__ offs, int* __restrict__ cursor,
                          int* __restrict__ srcs_sorted)
{
    int i = blockIdx.x * blockDim.x + threadIdx.x;
    if (i >= EE) return;
    int d = dst[i];
    int p = offs[d] + atomicAdd(&cursor[d], 1);
    srcs_sorted[p] = src[i];
}

// --------------- GAT aggregation: one wave per dst node, ALL heads -----------
template<int D, bool MEAN>
__global__ __launch_bounds__(256) void agg2_k(
    const unsigned short* __restrict__ zb, const float* __restrict__ el,
    const float* __restrict__ er, const int* __restrict__ offs,
    const int* __restrict__ srcs, const float* __restrict__ bias,
    unsigned short* __restrict__ outb, float* __restrict__ outf)
{
    constexpr int HD  = HH * D;
    constexpr int EPL = HD / 64;          // 8 for D=128, 4 for D=64
    typedef __attribute__((ext_vector_type(EPL))) unsigned short uvec;
    int n = blockIdx.x * 4 + (threadIdx.x >> 6);
    if (n >= NN) return;
    int lane = threadIdx.x & 63;
    int h = lane >> 4;
    int beg = offs[n];
    int cnt_e = offs[n + 1] - beg;
    float erh = er[n * HH + h];

    float acc[EPL] = {};
    float wsum = 0.f;

    if (cnt_e > 0) {
        auto LD = [&](int idx, uvec& v, float& elv) {
            int e = idx < cnt_e ? idx : cnt_e - 1;   // wave-uniform clamp
            int s = srcs[beg + e];
            elv = el[s * HH + h];
            v = *reinterpret_cast<const uvec*>(&zb[(size_t)s * HD + lane * EPL]);
        };
        auto PROC = [&](const uvec& v, float elv) {
            float x = elv + erh;
            x = x >= 0.f ? x : 0.2f * x;
            float ex = __expf(x);
            wsum += ex;
            #pragma unroll
            for (int j = 0; j < EPL; ++j)
                acc[j] = fmaf(ex, b2f(v[j]), acc[j]);
        };
        uvec v0, v1, v2, v3;
        float e0, e1, e2, e3;
        LD(0, v0, e0); LD(1, v1, e1); LD(2, v2, e2); LD(3, v3, e3);
        for (int c0 = 0; c0 < cnt_e; c0 += 4) {
            PROC(v0, e0); LD(c0 + 4, v0, e0);
            if (c0 + 1 < cnt_e) { PROC(v1, e1); } LD(c0 + 5, v1, e1);
            if (c0 + 2 < cnt_e) { PROC(v2, e2); } LD(c0 + 6, v2, e2);
            if (c0 + 3 < cnt_e) { PROC(v3, e3); } LD(c0 + 7, v3, e3);
        }
    }
    float inv = wsum > 0.f ? 1.f / wsum : 0.f;

    float vv[EPL];
    #pragma unroll
    for (int j = 0; j < EPL; ++j) {
        float v = acc[j] * inv + bias[h * D + (lane & 15) * EPL + j];
        vv[j] = v >= 0.f ? v : 0.01f * v;
    }

    if (!MEAN) {
        uvec u;
        #pragma unroll
        for (int j = 0; j < EPL; ++j) u[j] = f2b(vv[j]);
        *reinterpret_cast<uvec*>(&outb[(size_t)n * HD + lane * EPL]) = u;
    } else {
        #pragma unroll
        for (int j = 0; j < EPL; ++j) {
            float s = vv[j];
            s += __shfl_xor(s, 16);
            s += __shfl_xor(s, 32);
            s *= 0.25f;
            vv[j] = s >= 0.f ? s : 0.01f * s;
        }
        if (lane < 16) {
            float* op = outf + (size_t)n * D + lane * EPL;
            #pragma unroll
            for (int j = 0; j < EPL; j += 4)
                *reinterpret_cast<float4*>(op + j) =
                    make_float4(vv[j], vv[j + 1], vv[j + 2], vv[j + 3]);
        }
    }
}

// -----------------------------------------------------------------------------
extern "C" void kernel_launch(void* const* d_in, const int* in_sizes, int n_in,
                              void* d_out, int out_size, void* d_ws, size_t ws_size,
                              hipStream_t stream)
{
    const float* n_feat = (const float*)d_in[0];
    const int*   src    = (const int*)d_in[1];
    const int*   dst    = (const int*)d_in[2];
    const float* g0_W  = (const float*)d_in[3];
    const float* g0_al = (const float*)d_in[4];
    const float* g0_ar = (const float*)d_in[5];
    const float* g0_b  = (const float*)d_in[6];
    const float* d0_W  = (const float*)d_in[7];
    const float* d0_b  = (const float*)d_in[8];
    const float* g1_W  = (const float*)d_in[9];
    const float* g1_al = (const float*)d_in[10];
    const float* g1_ar = (const float*)d_in[11];
    const float* g1_b  = (const float*)d_in[12];
    const float* d1_W  = (const float*)d_in[13];
    const float* d1_b  = (const float*)d_in[14];
    const float* g2_W  = (const float*)d_in[15];
    const float* g2_al = (const float*)d_in[16];
    const float* g2_ar = (const float*)d_in[17];
    const float* g2_b  = (const float*)d_in[18];

    char* ws = (char*)d_ws;
    size_t off = 0;
    auto alloc = [&](size_t bytes) {
        void* p = ws + off;
        off += (bytes + 255) & ~(size_t)255;
        return p;
    };
    // Total ~135 MB (budget: 236 MB known-good).
    unsigned short* zB   = (unsigned short*)alloc((size_t)NN * 512 * 2); // proj out
    unsigned short* hB   = (unsigned short*)alloc((size_t)NN * 512 * 2); // agg out
    unsigned short* hC   = (unsigned short*)alloc((size_t)NN * 128 * 2); // dense out
    unsigned short* xF   = (unsigned short*)alloc((size_t)NN * 128 * 2); // n_feat bf16
    unsigned short* g0t  = (unsigned short*)alloc(512 * 128 * 2);
    unsigned short* g1t  = (unsigned short*)alloc(512 * 128 * 2);
    unsigned short* g2t  = (unsigned short*)alloc(256 * 128 * 2);
    unsigned short* d0t  = (unsigned short*)alloc(128 * 512 * 2);
    unsigned short* d1t  = (unsigned short*)alloc(128 * 512 * 2);
    float*          el   = (float*)alloc((size_t)NN * HH * 4);
    float*          er   = (float*)alloc((size_t)NN * HH * 4);
    int*            cnt  = (int*)alloc((size_t)NN * 4);
    int*            curs = (int*)alloc((size_t)NN * 4);
    int*            offs = (int*)alloc((size_t)(NN + 1) * 4);
    int*            srcs = (int*)alloc((size_t)EE * 4);
    int*            bsum = (int*)alloc(256 * 4);

    // ---- prep: CSR build + fused weight/feature casts ----
    hipMemsetAsync(cnt, 0, (size_t)NN * 4, stream);
    hist_k<<<(EE / 2 + 255) / 256, 256, 0, stream>>>(dst, cnt);
    scan1_k<<<SCAN_B, 256, 0, stream>>>(cnt, offs, bsum);
    scan2_k<<<1, 256, 0, stream>>>(bsum);
    scan3_k<<<SCAN_B, 256, 0, stream>>>(offs, bsum, curs);
    scatter_k<<<(EE + 255) / 256, 256, 0, stream>>>(src, dst, offs, curs, srcs);
    prep_k<<<(PREP_T + 255) / 256, 256, 0, stream>>>(
        n_feat, d0_W, d1_W, g0_W, g1_W, g2_W, xF, d0t, d1t, g0t, g1t, g2t);

    const int MT2  = (NN + 127) / 128;      // 391 row strips
    const int NODB = (NN + 3) / 4;

    // ---- layer 0 ----
    pgemm_k<4, 1><<<MT2, 256, 0, stream>>>(xF, g0t, zB, g0_al, g0_ar, el, er, NN);
    agg2_k<128, false><<<NODB, 256, 0, stream>>>(zB, el, er, offs, srcs, g0_b,
                                                 hB, nullptr);
    mgemm_k<true><<<dim3(1, MT2), 256, 0, stream>>>(
        hB, d0t, d0_b, hC, NN, 128, 512, 0.01f);

    // ---- layer 1 ----
    pgemm_k<4, 1><<<MT2, 256, 0, stream>>>(hC, g1t, zB, g1_al, g1_ar, el, er, NN);
    agg2_k<128, false><<<NODB, 256, 0, stream>>>(zB, el, er, offs, srcs, g1_b,
                                                 hB, nullptr);
    mgemm_k<true><<<dim3(1, MT2), 256, 0, stream>>>(
        hB, d1t, d1_b, hC, NN, 128, 512, 0.01f);

    // ---- layer 2 + fused bias/lrelu/mean/lrelu ----
    pgemm_k<2, 2><<<MT2, 256, 0, stream>>>(hC, g2t, zB, g2_al, g2_ar, el, er, NN);
    agg2_k<64, true><<<NODB, 256, 0, stream>>>(zB, el, er, offs, srcs, g2_b,
                                               nullptr, (float*)d_out);
}

// Round 11
// 526.200 us; speedup vs baseline: 1.0999x; 1.0999x over previous
//
#include <hip/hip_runtime.h>

#define NN 50000
#define EE 800000
#define HH 4

typedef __attribute__((ext_vector_type(8))) short short8v;     // 8 bf16 = 4 VGPR
typedef __attribute__((ext_vector_type(4))) float f32x4;
typedef __attribute__((ext_vector_type(4))) unsigned short ushort4v;

__device__ __forceinline__ float b2f(unsigned short u) {
    return __uint_as_float(((unsigned int)u) << 16);
}
__device__ __forceinline__ unsigned short f2b(float f) {
    unsigned int x = __float_as_uint(f);
    x += 0x7fffu + ((x >> 16) & 1u);
    return (unsigned short)(x >> 16);
}

// ---------------- bf16 MFMA GEMM: C[M,N] = A[M,K] @ Bt[N,K]^T ---------------
// BM=64*WR, BN=128, BK=64; 256 threads = 4 waves.
// Register double-buffer prefetch; LDS-staged coalesced C-write (16B stores).
// WEL=1: BN==D==128, block cols = one head -> fused el/er epilogue.
// WEL=2: D=64, block cols = two heads.
template<int WR, bool ACT, int WEL>
__global__ __launch_bounds__(256) void mgemm_k(
    const unsigned short* __restrict__ A, const unsigned short* __restrict__ Bt,
    const float* __restrict__ bias, unsigned short* __restrict__ C,
    const float* __restrict__ al, const float* __restrict__ ar,
    float* __restrict__ el, float* __restrict__ er,
    int M, int N, int K, float slope)
{
    constexpr int BM = 64 * WR;
    constexpr int NA = 2 * WR;                // A-chunks per thread
    __shared__ unsigned short smem[BM * 72 + 128 * 72];
    unsigned short* As = smem;                // [BM][72]
    unsigned short* Bs = smem + BM * 72;      // [128][72]
    unsigned short* Cs = smem;                // C-stage [BM][136], after last barrier
    const int t   = threadIdx.x;
    const int m0  = blockIdx.y * BM;
    const int n0  = blockIdx.x * 128;
    const int w   = t >> 6;
    const int l   = t & 63;
    const int lr  = l & 15;            // frag row (A) / col (B,C)
    const int lk8 = (l >> 4) * 8;      // frag k-offset
    const int wbase = w * 16 * WR;

    f32x4 acc[WR][8];
    #pragma unroll
    for (int rr = 0; rr < WR; ++rr)
        #pragma unroll
        for (int i = 0; i < 8; ++i) acc[rr][i] = (f32x4)0.f;

    short8v ra[NA], rb[4];
    auto LOAD = [&](int k0) {
        #pragma unroll
        for (int cc = 0; cc < NA; ++cc) {
            int c = t + cc * 256;
            int row = c >> 3, seg = (c & 7) * 8;
            int gm = m0 + row;
            ra[cc] = (short8v)0;
            if (gm < M)
                ra[cc] = *reinterpret_cast<const short8v*>(
                    &A[(size_t)gm * K + k0 + seg]);
        }
        #pragma unroll
        for (int cc = 0; cc < 4; ++cc) {
            int c = t + cc * 256;
            int row = c >> 3, seg = (c & 7) * 8;
            rb[cc] = *reinterpret_cast<const short8v*>(
                &Bt[(size_t)(n0 + row) * K + k0 + seg]);
        }
    };

    LOAD(0);
    for (int k0 = 0; k0 < K; k0 += 64) {
        #pragma unroll
        for (int cc = 0; cc < NA; ++cc) {
            int c = t + cc * 256;
            *reinterpret_cast<short8v*>(&As[(c >> 3) * 72 + (c & 7) * 8]) = ra[cc];
        }
        #pragma unroll
        for (int cc = 0; cc < 4; ++cc) {
            int c = t + cc * 256;
            *reinterpret_cast<short8v*>(&Bs[(c >> 3) * 72 + (c & 7) * 8]) = rb[cc];
        }
        __syncthreads();
        if (k0 + 64 < K) LOAD(k0 + 64);        // prefetch next tile during MFMA
        #pragma unroll
        for (int kk = 0; kk < 64; kk += 32) {
            short8v a[WR];
            #pragma unroll
            for (int rr = 0; rr < WR; ++rr)
                a[rr] = *reinterpret_cast<const short8v*>(
                    &As[(wbase + rr * 16 + lr) * 72 + kk + lk8]);
            #pragma unroll
            for (int nb = 0; nb < 8; ++nb) {
                short8v b = *reinterpret_cast<const short8v*>(
                    &Bs[(nb * 16 + lr) * 72 + kk + lk8]);
                #pragma unroll
                for (int rr = 0; rr < WR; ++rr)
                    acc[rr][nb] = __builtin_amdgcn_mfma_f32_16x16x32_bf16(
                        a[rr], b, acc[rr][nb], 0, 0, 0);
            }
        }
        __syncthreads();
    }

    // ---- fused el/er: dot acc rows with al/ar over this block's head cols ----
    if (WEL > 0) {
        const int nbh = (WEL == 1) ? 8 : 4;     // nb per head
        const int Dd  = (WEL == 1) ? 128 : 64;
        #pragma unroll
        for (int hh = 0; hh < WEL; ++hh) {
            int head = (WEL == 1) ? blockIdx.x : blockIdx.x * 2 + hh;
            #pragma unroll
            for (int rr = 0; rr < WR; ++rr) {
                float pl[4] = {}, pr[4] = {};
                #pragma unroll
                for (int nb = 0; nb < nbh; ++nb) {
                    float alv = al[head * Dd + nb * 16 + lr];
                    float arv = ar[head * Dd + nb * 16 + lr];
                    #pragma unroll
                    for (int r = 0; r < 4; ++r) {
                        float z = acc[rr][hh * nbh + nb][r];
                        pl[r] = fmaf(z, alv, pl[r]);
                        pr[r] = fmaf(z, arv, pr[r]);
                    }
                }
                #pragma unroll
                for (int r = 0; r < 4; ++r) {
                    #pragma unroll
                    for (int o = 1; o < 16; o <<= 1) {
                        pl[r] += __shfl_xor(pl[r], o);
                        pr[r] += __shfl_xor(pr[r], o);
                    }
                }
                if (lr == 0) {
                    #pragma unroll
                    for (int r = 0; r < 4; ++r) {
                        int gm = m0 + wbase + rr * 16 + (l >> 4) * 4 + r;
                        if (gm < M) {
                            el[gm * HH + head] = pl[r];
                            er[gm * HH + head] = pr[r];
                        }
                    }
                }
            }
        }
    }

    // ---- C-write: stage tile in LDS (As/Bs dead), then 16B coalesced stores --
    #pragma unroll
    for (int rr = 0; rr < WR; ++rr) {
        #pragma unroll
        for (int nb = 0; nb < 8; ++nb) {
            #pragma unroll
            for (int r = 0; r < 4; ++r) {
                int row = wbase + rr * 16 + (l >> 4) * 4 + r;
                int gn = n0 + nb * 16 + lr;
                float v = acc[rr][nb][r];
                if (ACT) { v += bias[gn]; v = v >= 0.f ? v : slope * v; }
                Cs[row * 136 + nb * 16 + lr] = f2b(v);
            }
        }
    }
    __syncthreads();
    constexpr int NC = BM / 16;               // 16B chunks per thread
    #pragma unroll
    for (int cc = 0; cc < NC; ++cc) {
        int c = t + cc * 256;
        int row = c >> 4, seg = (c & 15) * 8;
        int gm = m0 + row;
        if (gm < M) {
            short8v v = *reinterpret_cast<const short8v*>(&Cs[row * 136 + seg]);
            *reinterpret_cast<short8v*>(&C[(size_t)gm * N + n0 + seg]) = v;
        }
    }
}

// ---------------- fused weight/feature prep (1 launch) -----------------------
#define PREP_T 1796608
__global__ __launch_bounds__(256) void prep_k(
    const float* __restrict__ n_feat, const float* __restrict__ d0_W,
    const float* __restrict__ d1_W, const float* __restrict__ g0_W,
    const float* __restrict__ g1_W, const float* __restrict__ g2_W,
    unsigned short* __restrict__ xF, unsigned short* __restrict__ d0t,
    unsigned short* __restrict__ d1t, unsigned short* __restrict__ g0t,
    unsigned short* __restrict__ g1t, unsigned short* __restrict__ g2t)
{
    int i = blockIdx.x * blockDim.x + threadIdx.x;
    if (i >= PREP_T) return;
    if (i < 1632768) {
        const float* src; unsigned short* dstp; int j;
        if (i < 1600000)      { src = n_feat; dstp = xF;  j = i; }
        else if (i < 1616384) { src = d0_W;   dstp = d0t; j = i - 1600000; }
        else                  { src = d1_W;   dstp = d1t; j = i - 1616384; }
        float4 v = reinterpret_cast<const float4*>(src)[j];
        ushort4v u;
        u[0] = f2b(v.x); u[1] = f2b(v.y); u[2] = f2b(v.z); u[3] = f2b(v.w);
        reinterpret_cast<ushort4v*>(dstp)[j] = u;
    } else {
        const float* W; unsigned short* Wt; int j, K = 128;
        if (i < 1698304)      { W = g0_W; Wt = g0t; j = i - 1632768; }
        else if (i < 1763840) { W = g1_W; Wt = g1t; j = i - 1698304; }
        else                  { W = g2_W; Wt = g2t; j = i - 1763840; }
        int N = (i < 1763840) ? 512 : 256;
        int n = j / K, k = j - n * K;
        Wt[j] = f2b(W[(size_t)k * N + n]);
    }
}

// --------------- CSR build ---------------------------------------------------
__global__ void hist_k(const int* __restrict__ dst, int* __restrict__ cnt)
{
    int i = blockIdx.x * blockDim.x + threadIdx.x;
    if (i < EE / 4) {
        int4 d = reinterpret_cast<const int4*>(dst)[i];
        atomicAdd(&cnt[d.x], 1);
        atomicAdd(&cnt[d.y], 1);
        atomicAdd(&cnt[d.z], 1);
        atomicAdd(&cnt[d.w], 1);
    }
}

#define SCAN_B 196   // ceil(50000/256)
__global__ __launch_bounds__(256) void scan1_k(const int* __restrict__ cnt,
                                               int* __restrict__ offs,
                                               int* __restrict__ bsum)
{
    __shared__ int sh[256];
    int b = blockIdx.x, t = threadIdx.x, i = b * 256 + t;
    int v = (i < NN) ? cnt[i] : 0;
    sh[t] = v;
    __syncthreads();
    #pragma unroll
    for (int o = 1; o < 256; o <<= 1) {
        int add = (t >= o) ? sh[t - o] : 0;
        __syncthreads();
        sh[t] += add;
        __syncthreads();
    }
    if (i < NN) offs[i] = sh[t] - v;
    if (t == 255) bsum[b] = sh[t];
}

__global__ __launch_bounds__(256) void scan2_k(int* __restrict__ bsum)
{
    __shared__ int sh[256];
    int t = threadIdx.x;
    int v = (t < SCAN_B) ? bsum[t] : 0;
    sh[t] = v;
    __syncthreads();
    #pragma unroll
    for (int o = 1; o < 256; o <<= 1) {
        int add = (t >= o) ? sh[t - o] : 0;
        __syncthreads();
        sh[t] += add;
        __syncthreads();
    }
    if (t < SCAN_B) bsum[t] = sh[t] - v;
}

__global__ __launch_bounds__(256) void scan3_k(int* __restrict__ offs,
                                               const int* __restrict__ bsum,
                                               int* __restrict__ curs)
{
    int b = blockIdx.x, t = threadIdx.x, i = b * 256 + t;
    if (i < NN) { offs[i] += bsum[b]; curs[i] = 0; }
    if (i == NN - 1) offs[NN] = EE;
}

__global__ void scatter_k(const int* __restrict__ src, const int* __restrict__ dst,
                          const int* __restrict__ offs, int* __restrict__ cursor,
                          int* __restrict__ srcs_sorted)
{
    int i = blockIdx.x * blockDim.x + threadIdx.x;
    if (i >= EE) return;
    int d = dst[i];
    int p = offs[d] + atomicAdd(&cursor[d], 1);
    srcs_sorted[p] = src[i];
}

// --------------- GAT aggregation: one wave per dst node, ALL heads -----------
template<int D, bool MEAN>
__global__ __launch_bounds__(256) void agg2_k(
    const unsigned short* __restrict__ zb, const float* __restrict__ el,
    const float* __restrict__ er, const int* __restrict__ offs,
    const int* __restrict__ srcs, const float* __restrict__ bias,
    unsigned short* __restrict__ outb, float* __restrict__ outf)
{
    constexpr int HD  = HH * D;
    constexpr int EPL = HD / 64;          // 8 for D=128, 4 for D=64
    typedef __attribute__((ext_vector_type(EPL))) unsigned short uvec;
    int n = blockIdx.x * 4 + (threadIdx.x >> 6);
    if (n >= NN) return;
    int lane = threadIdx.x & 63;
    int h = lane >> 4;
    int beg = offs[n];
    int cnt_e = offs[n + 1] - beg;
    float erh = er[n * HH + h];

    float acc[EPL] = {};
    float wsum = 0.f;

    if (cnt_e > 0) {
        auto LD = [&](int idx, uvec& v, float& elv) {
            int e = idx < cnt_e ? idx : cnt_e - 1;   // wave-uniform clamp
            int s = srcs[beg + e];
            elv = el[s * HH + h];
            v = *reinterpret_cast<const uvec*>(&zb[(size_t)s * HD + lane * EPL]);
        };
        auto PROC = [&](const uvec& v, float elv) {
            float x = elv + erh;
            x = x >= 0.f ? x : 0.2f * x;
            float ex = __expf(x);
            wsum += ex;
            #pragma unroll
            for (int j = 0; j < EPL; ++j)
                acc[j] = fmaf(ex, b2f(v[j]), acc[j]);
        };
        uvec v0, v1, v2, v3;
        float e0, e1, e2, e3;
        LD(0, v0, e0); LD(1, v1, e1); LD(2, v2, e2); LD(3, v3, e3);
        for (int c0 = 0; c0 < cnt_e; c0 += 4) {
            PROC(v0, e0); LD(c0 + 4, v0, e0);
            if (c0 + 1 < cnt_e) { PROC(v1, e1); } LD(c0 + 5, v1, e1);
            if (c0 + 2 < cnt_e) { PROC(v2, e2); } LD(c0 + 6, v2, e2);
            if (c0 + 3 < cnt_e) { PROC(v3, e3); } LD(c0 + 7, v3, e3);
        }
    }
    float inv = wsum > 0.f ? 1.f / wsum : 0.f;

    float vv[EPL];
    #pragma unroll
    for (int j = 0; j < EPL; ++j) {
        float v = acc[j] * inv + bias[h * D + (lane & 15) * EPL + j];
        vv[j] = v >= 0.f ? v : 0.01f * v;
    }

    if (!MEAN) {
        uvec u;
        #pragma unroll
        for (int j = 0; j < EPL; ++j) u[j] = f2b(vv[j]);
        *reinterpret_cast<uvec*>(&outb[(size_t)n * HD + lane * EPL]) = u;
    } else {
        #pragma unroll
        for (int j = 0; j < EPL; ++j) {
            float s = vv[j];
            s += __shfl_xor(s, 16);
            s += __shfl_xor(s, 32);
            s *= 0.25f;
            vv[j] = s >= 0.f ? s : 0.01f * s;
        }
        if (lane < 16) {
            float* op = outf + (size_t)n * D + lane * EPL;
            #pragma unroll
            for (int j = 0; j < EPL; j += 4)
                *reinterpret_cast<float4*>(op + j) =
                    make_float4(vv[j], vv[j + 1], vv[j + 2], vv[j + 3]);
        }
    }
}

// -----------------------------------------------------------------------------
extern "C" void kernel_launch(void* const* d_in, const int* in_sizes, int n_in,
                              void* d_out, int out_size, void* d_ws, size_t ws_size,
                              hipStream_t stream)
{
    const float* n_feat = (const float*)d_in[0];
    const int*   src    = (const int*)d_in[1];
    const int*   dst    = (const int*)d_in[2];
    const float* g0_W  = (const float*)d_in[3];
    const float* g0_al = (const float*)d_in[4];
    const float* g0_ar = (const float*)d_in[5];
    const float* g0_b  = (const float*)d_in[6];
    const float* d0_W  = (const float*)d_in[7];
    const float* d0_b  = (const float*)d_in[8];
    const float* g1_W  = (const float*)d_in[9];
    const float* g1_al = (const float*)d_in[10];
    const float* g1_ar = (const float*)d_in[11];
    const float* g1_b  = (const float*)d_in[12];
    const float* d1_W  = (const float*)d_in[13];
    const float* d1_b  = (const float*)d_in[14];
    const float* g2_W  = (const float*)d_in[15];
    const float* g2_al = (const float*)d_in[16];
    const float* g2_ar = (const float*)d_in[17];
    const float* g2_b  = (const float*)d_in[18];

    char* ws = (char*)d_ws;
    size_t off = 0;
    auto alloc = [&](size_t bytes) {
        void* p = ws + off;
        off += (bytes + 255) & ~(size_t)255;
        return p;
    };
    // Total ~135 MB (budget: 236 MB known-good).
    unsigned short* zB   = (unsigned short*)alloc((size_t)NN * 512 * 2); // proj out
    unsigned short* hB   = (unsigned short*)alloc((size_t)NN * 512 * 2); // agg out
    unsigned short* hC   = (unsigned short*)alloc((size_t)NN * 128 * 2); // dense out
    unsigned short* xF   = (unsigned short*)alloc((size_t)NN * 128 * 2); // n_feat bf16
    unsigned short* g0t  = (unsigned short*)alloc(512 * 128 * 2);
    unsigned short* g1t  = (unsigned short*)alloc(512 * 128 * 2);
    unsigned short* g2t  = (unsigned short*)alloc(256 * 128 * 2);
    unsigned short* d0t  = (unsigned short*)alloc(128 * 512 * 2);
    unsigned short* d1t  = (unsigned short*)alloc(128 * 512 * 2);
    float*          el   = (float*)alloc((size_t)NN * HH * 4);
    float*          er   = (float*)alloc((size_t)NN * HH * 4);
    int*            cnt  = (int*)alloc((size_t)NN * 4);
    int*            curs = (int*)alloc((size_t)NN * 4);
    int*            offs = (int*)alloc((size_t)(NN + 1) * 4);
    int*            srcs = (int*)alloc((size_t)EE * 4);
    int*            bsum = (int*)alloc(256 * 4);

    // ---- prep: CSR build + fused weight/feature casts ----
    hipMemsetAsync(cnt, 0, (size_t)NN * 4, stream);
    hist_k<<<(EE / 4 + 255) / 256, 256, 0, stream>>>(dst, cnt);
    scan1_k<<<SCAN_B, 256, 0, stream>>>(cnt, offs, bsum);
    scan2_k<<<1, 256, 0, stream>>>(bsum);
    scan3_k<<<SCAN_B, 256, 0, stream>>>(offs, bsum, curs);
    scatter_k<<<(EE + 255) / 256, 256, 0, stream>>>(src, dst, offs, curs, srcs);
    prep_k<<<(PREP_T + 255) / 256, 256, 0, stream>>>(
        n_feat, d0_W, d1_W, g0_W, g1_W, g2_W, xF, d0t, d1t, g0t, g1t, g2t);

    const int MT2  = (NN + 127) / 128;      // 391 row tiles (WR=2)
    const int NODB = (NN + 3) / 4;

    // ---- layer 0 ----
    mgemm_k<2, false, 1><<<dim3(4, MT2), 256, 0, stream>>>(
        xF, g0t, nullptr, zB, g0_al, g0_ar, el, er, NN, 512, 128, 0.f);
    agg2_k<128, false><<<NODB, 256, 0, stream>>>(zB, el, er, offs, srcs, g0_b,
                                                 hB, nullptr);
    mgemm_k<2, true, 0><<<dim3(1, MT2), 256, 0, stream>>>(
        hB, d0t, d0_b, hC, nullptr, nullptr, nullptr, nullptr, NN, 128, 512, 0.01f);

    // ---- layer 1 ----
    mgemm_k<2, false, 1><<<dim3(4, MT2), 256, 0, stream>>>(
        hC, g1t, nullptr, zB, g1_al, g1_ar, el, er, NN, 512, 128, 0.f);
    agg2_k<128, false><<<NODB, 256, 0, stream>>>(zB, el, er, offs, srcs, g1_b,
                                                 hB, nullptr);
    mgemm_k<2, true, 0><<<dim3(1, MT2), 256, 0, stream>>>(
        hB, d1t, d1_b, hC, nullptr, nullptr, nullptr, nullptr, NN, 128, 512, 0.01f);

    // ---- layer 2 + fused bias/lrelu/mean/lrelu ----
    mgemm_k<2, false, 2><<<dim3(2, MT2), 256, 0, stream>>>(
        hC, g2t, nullptr, zB, g2_al, g2_ar, el, er, NN, 256, 128, 0.f);
    agg2_k<64, true><<<NODB, 256, 0, stream>>>(zB, el, er, offs, srcs, g2_b,
                                               nullptr, (float*)d_out);
}